// Round 4
// baseline (149.510 us; speedup 1.0000x reference)
//
#include <hip/hip_runtime.h>
#include <hip/hip_bf16.h>

// SoftRAM attention: S=128, B=256 bits, H=16 heads, NB=12 bits/neuron, PB=7.
// addr(i,j,h,n) = aq[i] | ak[j] | ap[i-j] (disjoint bit groups per (h,n));
// only sign(memory) matters -> byte-LUT (0/1) per (h,n) in LDS.
//
// R4: single kernel (no d_ws -> avoid 256MB poison-fill interference).
// Block = 1024 (16 waves), grid = 256 (one n-column per block).
// Phase D: 2 waves/head x 2 j-mod-4 parity streams/lane -> 33-iter loop with
// 2 independent lookup chains (MLP fix for the latency-bound chain).
// Byte-LUT: lookup is one ds_read_u8 (no bit extraction).
// 2 head-rounds (0..7, 8..15) with VGPR prefetch of round-2 LUT rows issued
// before round-1 compute -> HBM read overlaps Phase D.

#define S 128
#define B 256
#define H 16
#define NB 12

__global__ __launch_bounds__(1024, 4) void softram_kernel(
    const int* __restrict__ tokens,        // [S,B] 0/1
    const float* __restrict__ memory,      // [H,B,4096]
    const int* __restrict__ connections,   // [H,B,NB]
    int* __restrict__ out)                 // [S,B] 0/1
{
    const int n = blockIdx.x;
    const int tid = threadIdx.x;

    // Declaration order matters: masked-out OOB indices from the uniform loop
    // land in adjacent arrays (aks[h][131], aps[h][imj&255]) -- all in-LDS.
    __shared__ unsigned char  lutb[8 * 4096];   // 32 KB: byte LUT, per-round
    __shared__ unsigned int   tok[S * 8];       // 4 KB: packed token bits
    __shared__ unsigned short aks[H][S];        // 4 KB
    __shared__ unsigned short aps[H][S];        // 4 KB
    __shared__ unsigned short aqs[H][S];        // 4 KB
    __shared__ int            conns[H][NB];     // 768 B
    __shared__ unsigned char  parts[H][2][S];   // 4 KB: per (head, wave-half)

    // ---- Phase B1: heads 0..7 -> byte LUT; tok pack; conns ----
    {
        float4 v[8];
        #pragma unroll
        for (int q = 0; q < 8; ++q) {
            const float4* mrow = (const float4*)(memory + ((size_t)((q << 8) | n) << 12));
            v[q] = mrow[tid];
        }
        // token pack: thread -> one dword of 32 token bits
        {
            int i = tid >> 3, w = tid & 7;
            const int4* tp = (const int4*)tokens;
            unsigned int t = 0;
            #pragma unroll
            for (int u = 0; u < 8; ++u) {
                int4 x = tp[i * 64 + w * 8 + u];
                t |= (unsigned int)(x.x & 1) << (4 * u + 0);
                t |= (unsigned int)(x.y & 1) << (4 * u + 1);
                t |= (unsigned int)(x.z & 1) << (4 * u + 2);
                t |= (unsigned int)(x.w & 1) << (4 * u + 3);
            }
            tok[tid] = t;
        }
        if (tid < H * NB) {
            int h = tid / NB, b = tid - h * NB;
            conns[h][b] = connections[h * (B * NB) + n * NB + b];
        }
        unsigned int* lw = (unsigned int*)lutb;
        #pragma unroll
        for (int q = 0; q < 8; ++q) {
            unsigned int w = (unsigned int)(v[q].x > 0.f)
                           | ((unsigned int)(v[q].y > 0.f) << 8)
                           | ((unsigned int)(v[q].z > 0.f) << 16)
                           | ((unsigned int)(v[q].w > 0.f) << 24);
            lw[(q << 10) + tid] = w;
        }
    }
    __syncthreads();

    // ---- Phase C: aq/ak/ap tables for all 16 heads (2 entries/thread) ----
    #pragma unroll
    for (int e0 = 0; e0 < 2; ++e0) {
        int e = tid + (e0 << 10);
        int h = e >> 7, ii = e & 127;      // h wave-uniform -> uniform branches
        unsigned int aq = 0, ak = 0, ap = 0;
        #pragma unroll
        for (int b = 0; b < NB; ++b) {
            int c = conns[h][b];
            if (c < 256) {
                aq |= ((tok[ii * 8 + (c >> 5)] >> (c & 31)) & 1u) << b;
            } else if (c < 512) {
                int c2 = c - 256;
                ak |= ((tok[ii * 8 + (c2 >> 5)] >> (c2 & 31)) & 1u) << b;
            } else {
                ap |= (unsigned int)((ii >> (c - 512)) & 1) << b;
            }
        }
        aqs[h][ii] = (unsigned short)aq;
        aks[h][ii] = (unsigned short)ak;
        aps[h][ii] = (unsigned short)ap;
    }
    __syncthreads();

    const int wave = tid >> 6, lane = tid & 63;
    const int hl = wave >> 1;              // local head 0..7
    const int r2 = wave & 1;               // stream pair selector
    const int i0 = lane, i1 = 127 - lane;

    // ---- Prefetch round-2 LUT rows (heads 8..15) into VGPRs ----
    // Issued before round-1 Phase D; the barrier-drain lands after D0 compute.
    float4 pre[8];
    #pragma unroll
    for (int q = 0; q < 8; ++q) {
        const float4* mrow = (const float4*)(memory + ((size_t)(((8 + q) << 8) | n) << 12));
        pre[q] = mrow[tid];
    }

    // ---- Phase D: 2 parity streams (j mod 4 in {r2, r2+2}) per lane ----
    auto phaseD = [&](int h) {
        const unsigned int aq0 = aqs[h][i0];
        const unsigned int aq1 = aqs[h][i1];
        const unsigned short* __restrict__ akrow = &aks[h][0];
        const unsigned short* __restrict__ aprow = &aps[h][0];
        const unsigned char*  __restrict__ lrow  = &lutb[hl << 12];
        int c0a[2], cta[2], c04a[2];
        #pragma unroll
        for (int s = 0; s < 2; ++s) {
            int r  = r2 + 2 * s;
            int c0 = (i0 >= r) ? (((i0 - r) >> 2) + 1) : 0;  // #j<=i0, j==r mod4
            int c1 = ((i1 - r) >> 2) + 1;                     // #j<=i1 (i1>=64>r)
            c0a[s] = c0; cta[s] = c0 + c1; c04a[s] = c0 << 2;
        }
        unsigned int acc = 0;   // bit0: row-i0 parity, bit16: row-i1 parity
        #pragma unroll 11
        for (int k = 0; k < 33; ++k) {
            #pragma unroll
            for (int s = 0; s < 2; ++s) {
                const int r = r2 + 2 * s;
                bool first = k < c0a[s];
                bool valid = k < cta[s];
                int jb  = r + 4 * k;
                int j   = first ? jb : (jb - c04a[s]);   // j>=0 always
                int ii  = first ? i0 : i1;
                int imj = (ii - j) & 255;                // mask only hits invalid iters
                unsigned int aqv  = first ? aq0 : aq1;
                unsigned int akv  = akrow[j];
                unsigned int apv  = aprow[imj];
                unsigned int addr = (aqv | akv | apv) & 4095;
                unsigned int bit  = lrow[addr];          // 0/1 byte
                unsigned int contrib = bit << (first ? 0 : 16);
                acc ^= valid ? contrib : 0u;
            }
        }
        parts[h][r2][i0] = (unsigned char)(acc & 1u);
        parts[h][r2][i1] = (unsigned char)((acc >> 16) & 1u);
    };

    phaseD(hl);            // round 0: heads 0..7 (prefetch in flight)
    __syncthreads();       // D0 done everywhere; prefetch drained here

    // ---- Phase B2: write heads 8..15 byte LUT from prefetched regs ----
    {
        unsigned int* lw = (unsigned int*)lutb;
        #pragma unroll
        for (int q = 0; q < 8; ++q) {
            unsigned int w = (unsigned int)(pre[q].x > 0.f)
                           | ((unsigned int)(pre[q].y > 0.f) << 8)
                           | ((unsigned int)(pre[q].z > 0.f) << 16)
                           | ((unsigned int)(pre[q].w > 0.f) << 24);
            lw[(q << 10) + tid] = w;
        }
    }
    __syncthreads();

    phaseD(8 + hl);        // round 1: heads 8..15
    __syncthreads();

    // ---- Epilogue: majority vote across 16 heads ----
    if (tid < S) {
        int tot = 0;
        #pragma unroll
        for (int h = 0; h < H; ++h)
            tot += parts[h][0][tid] ^ parts[h][1][tid];
        out[tid * B + n] = (tot > (H / 2)) ? 1 : 0;
    }
}

extern "C" void kernel_launch(void* const* d_in, const int* in_sizes, int n_in,
                              void* d_out, int out_size, void* d_ws, size_t ws_size,
                              hipStream_t stream) {
    const int*   tokens      = (const int*)d_in[0];
    const float* memory      = (const float*)d_in[1];
    const int*   connections = (const int*)d_in[2];
    int*         out         = (int*)d_out;
    (void)in_sizes; (void)n_in; (void)out_size; (void)d_ws; (void)ws_size;

    softram_kernel<<<B, 1024, 0, stream>>>(tokens, memory, connections, out);
}

// Round 5
// 114.337 us; speedup vs baseline: 1.3076x; 1.3076x over previous
//
#include <hip/hip_runtime.h>
#include <hip/hip_bf16.h>

// SoftRAM attention: S=128, B=256 bits, H=16 heads, NB=12 bits/neuron, PB=7.
// addr(i,j,h,n) = aq[i] | ak[j] | ap[i-j] (disjoint bit groups per (h,n));
// only sign(memory) matters -> byte-LUT per (h,n).
//
// R5: async-pipelined staging. global_load_lds (deep queue, no VGPRs -- the
// R4 register-prefetch spilled to scratch, 108MB writes) stages 2 heads/round
// into a double-buffered raw LDS region; round r issues round r+2's loads
// before Phase D so the pre-barrier vmcnt drain overlaps compute.
// Phase D: wave = (head, j mod 8) -> 17-iter fully-unrolled loop, 17
// independent ds chains per lane. Byte-LUT: lookup = 1 ds_read_u8.

#define S 128
#define B 256
#define H 16
#define NB 12

typedef __attribute__((address_space(3))) void       lds_void;
typedef const __attribute__((address_space(1))) void glb_void;

__device__ __forceinline__ void async16(const float* g, float* l) {
    __builtin_amdgcn_global_load_lds((glb_void*)g, (lds_void*)l, 16, 0, 0);
}

__global__ __launch_bounds__(1024) void softram_kernel(
    const int* __restrict__ tokens,        // [S,B] 0/1
    const float* __restrict__ memory,      // [H,B,4096]
    const int* __restrict__ connections,   // [H,B,NB]
    int* __restrict__ out)                 // [S,B] 0/1
{
    const int n    = blockIdx.x;
    const int tid  = threadIdx.x;
    const int wv   = tid >> 6;
    const int lane = tid & 63;

    __shared__ float          raw[2][8192];        // 64 KB: 2-head raw f32, dbuf
    __shared__ unsigned char  lutb[8192];          // 8 KB: 2-head byte LUT
    __shared__ unsigned int   tok[S * 8];          // 4 KB: packed token bits
    __shared__ unsigned short aks[H][S];           // 4 KB
    __shared__ unsigned short aps[H][S];           // 4 KB (adjacent to aks)
    __shared__ unsigned short aqs[H][S];           // 4 KB
    __shared__ int            conns[H][NB];        // 768 B
    __shared__ unsigned char  parts_r[2][S][8];    // 2 KB: [hh][i][res]
    __shared__ unsigned char  parts_all[S][H];     // 2 KB: [i][h]

    // Issue async loads for round r (heads 2r, 2r+1 -> 32 KB) into raw[buf].
    // 32 chunks of 1 KB; wave wv issues chunks 2wv, 2wv+1 (lds base uniform).
    auto issue_round = [&](int r, int buf) {
        #pragma unroll
        for (int q = 0; q < 2; ++q) {
            int c = wv * 2 + q;                    // 0..31
            int h = 2 * r + (c >> 4);
            const float* g = memory + ((size_t)(h * 256 + n) << 12)
                           + ((c & 15) << 8) + (lane << 2);
            float* l = &raw[buf][c << 8];
            async16(g, l);
        }
    };

    // Pack raw[buf] (8192 floats, 2 heads) -> lutb bytes. 8 floats/thread.
    auto pack_round = [&](int buf) {
        const float4* rp = (const float4*)&raw[buf][0];
        float4 a = rp[2 * tid], b4 = rp[2 * tid + 1];
        unsigned w0 = (unsigned)(a.x > 0.f)        | ((unsigned)(a.y > 0.f) << 8)
                    | ((unsigned)(a.z > 0.f) << 16)| ((unsigned)(a.w > 0.f) << 24);
        unsigned w1 = (unsigned)(b4.x > 0.f)       | ((unsigned)(b4.y > 0.f) << 8)
                    | ((unsigned)(b4.z > 0.f) << 16)|((unsigned)(b4.w > 0.f) << 24);
        ((uint2*)lutb)[tid] = make_uint2(w0, w1);
    };

    // ---- Preamble ----
    issue_round(0, 0);
    {   // token bit-pack: thread -> one dword (32 token bits)
        int i = tid >> 3, w = tid & 7;
        const int4* tp = (const int4*)tokens;
        unsigned int t = 0;
        #pragma unroll
        for (int u = 0; u < 8; ++u) {
            int4 x = tp[i * 64 + w * 8 + u];
            t |= (unsigned)(x.x & 1) << (4 * u + 0);
            t |= (unsigned)(x.y & 1) << (4 * u + 1);
            t |= (unsigned)(x.z & 1) << (4 * u + 2);
            t |= (unsigned)(x.w & 1) << (4 * u + 3);
        }
        tok[tid] = t;
    }
    if (tid < H * NB) {
        int h = tid / NB, b = tid - h * NB;
        conns[h][b] = connections[h * (B * NB) + n * NB + b];
    }
    __syncthreads();                 // R0 in raw[0]; tok, conns ready

    issue_round(1, 1);

    // Tables for all 16 heads (2 entries/thread; h wave-uniform -> uniform br).
    #pragma unroll
    for (int e0 = 0; e0 < 2; ++e0) {
        int e = tid + (e0 << 10);
        int h = e >> 7, ii = e & 127;
        unsigned aq = 0, ak = 0, ap = 0;
        #pragma unroll
        for (int b = 0; b < NB; ++b) {
            int c = conns[h][b];
            if (c < 256) {
                aq |= ((tok[ii * 8 + (c >> 5)] >> (c & 31)) & 1u) << b;
            } else if (c < 512) {
                int c2 = c - 256;
                ak |= ((tok[ii * 8 + (c2 >> 5)] >> (c2 & 31)) & 1u) << b;
            } else {
                ap |= (unsigned)((ii >> (c - 512)) & 1) << b;
            }
        }
        aqs[h][ii] = (unsigned short)aq;
        aks[h][ii] = (unsigned short)ak;
        aps[h][ii] = (unsigned short)ap;
    }
    pack_round(0);                   // heads 0,1 -> lutb
    __syncthreads();                 // R1 drained; lutb + tables visible

    // ---- Main pipelined rounds ----
    const int hh  = wv >> 3;         // local head 0/1
    const int res = wv & 7;          // j mod 8
    const int i0 = lane, i1 = 127 - lane;
    const int c0 = (i0 >= res) ? (((i0 - res) >> 3) + 1) : 0;  // #j<=i0, j==res(8)
    const int ct = c0 + (((i1 - res) >> 3) + 1);               // + #j<=i1
    const unsigned char* __restrict__ lrow = &lutb[hh << 12];

    for (int r = 0; r < 8; ++r) {
        if (r < 6) issue_round(r + 2, r & 1);   // fetch overlaps D below

        const int h = 2 * r + hh;
        const unsigned aq0 = aqs[h][i0], aq1 = aqs[h][i1];
        const unsigned short* __restrict__ akr = &aks[h][0];
        const unsigned short* __restrict__ apr = &aps[h][0];
        unsigned accA = 0, accB = 0;
        #pragma unroll
        for (int k = 0; k < 17; ++k) {
            bool first = (k < c0);
            int j   = res + ((first ? k : (k - c0)) << 3);
            int ii  = first ? i0 : i1;
            int imj = (ii - j) & 127;           // masked iters only
            j &= 127;
            unsigned addr = (first ? aq0 : aq1) | akr[j] | apr[imj];
            unsigned v  = lrow[addr & 4095];
            unsigned vv = (k < ct) ? v : 0u;
            accA ^= first ? vv : 0u;
            accB ^= first ? 0u : vv;
        }
        parts_r[hh][i0][res] = (unsigned char)(accA & 1u);
        parts_r[hh][i1][res] = (unsigned char)(accB & 1u);

        __syncthreads();             // D(r) done; R(r+2) drained

        if (tid < 2 * S) {           // fold 8 residue parities -> head parity
            int ph = tid >> 7, i = tid & 127;
            uint2 pw = ((const uint2*)&parts_r[ph][i][0])[0];
            unsigned x = pw.x ^ pw.y;
            x ^= x >> 16; x ^= x >> 8;
            parts_all[i][2 * r + ph] = (unsigned char)(x & 1u);
        }
        if (r < 7) pack_round((r + 1) & 1);     // next 2 heads -> lutb

        __syncthreads();             // lutb ready; parts_r free for next D
    }

    // ---- Epilogue: majority vote across 16 heads ----
    if (tid < S) {
        const unsigned char* pa = &parts_all[tid][0];
        int tot = 0;
        #pragma unroll
        for (int h2 = 0; h2 < H; ++h2) tot += pa[h2];
        out[tid * B + n] = (tot > (H / 2)) ? 1 : 0;
    }
}

extern "C" void kernel_launch(void* const* d_in, const int* in_sizes, int n_in,
                              void* d_out, int out_size, void* d_ws, size_t ws_size,
                              hipStream_t stream) {
    const int*   tokens      = (const int*)d_in[0];
    const float* memory      = (const float*)d_in[1];
    const int*   connections = (const int*)d_in[2];
    int*         out         = (int*)d_out;
    (void)in_sizes; (void)n_in; (void)out_size; (void)d_ws; (void)ws_size;

    softram_kernel<<<B, 1024, 0, stream>>>(tokens, memory, connections, out);
}